// Round 4
// baseline (198.394 us; speedup 1.0000x reference)
//
#include <hip/hip_runtime.h>

#define PI2 6.28318530717958647692f

// ===========================================================================
// Kernel 1: per (b,t) plane.
// Phase 1: A2[kxi][w] = sum_{h<64} (X[h][w] + (-1)^kx X[h+64][w]) e^{-2pi i kx h/128}
//          thread = (kp 0..15, wq 0..15): kxi {2kp,2kp+1}, w {8wq..8wq+7}.
//          Twiddles by register recurrence (reset at h=32, exact quarter turn).
// Phase 2: Xf[kxi][ky] = sum_{w<64} (A2[w] + (-1)^ky A2[w+64]) e^{-2pi i ky w/128}
// kxi 0..15 -> kx=kxi ; kxi 16..31 -> kx=kxi+96. Scale 1/16384.
// Xf layout: [plane][kxi][ky][ri] (1024 dwords/plane).
// ===========================================================================
__global__ __launch_bounds__(256) void k_fwd(const float* __restrict__ X,
                                             float* __restrict__ Xf) {
  __shared__ __attribute__((aligned(16))) float A2t[32 * 130 * 2];  // [kxi][w pad130] f2, 33 KB
  const int plane = blockIdx.x;
  const int tid = threadIdx.x;
  const float* Xp = X + (size_t)plane * (128 * 128);

  // ---- phase 1 ----
  {
    const int kp = tid >> 4;          // 0..15
    const int wq = tid & 15;          // 0..15
    const int w0 = wq * 8;
    const int kie = 2 * kp;           // even kxi
    const int kxe = kie + ((kie & 16) ? 96 : 0);
    const int kxo = kxe + 1;
    float der, dei, dor_, doi;        // per-step twiddles e^{-2pi i kx/128}
    __sincosf(-PI2 * (float)kxe * (1.f / 128.f), &dei, &der);
    __sincosf(-PI2 * (float)kxo * (1.f / 128.f), &doi, &dor_);
    float aer[8], aei[8], aor[8], aoi[8];
    #pragma unroll
    for (int j = 0; j < 8; ++j) { aer[j] = aei[j] = aor[j] = aoi[j] = 0.f; }

    float4 xa0 = *(const float4*)&Xp[w0];
    float4 xa1 = *(const float4*)&Xp[w0 + 4];
    float4 xb0 = *(const float4*)&Xp[64 * 128 + w0];
    float4 xb1 = *(const float4*)&Xp[64 * 128 + w0 + 4];
    float Ter = 1.f, Tei = 0.f, Tor = 1.f, Toi = 0.f;

    for (int h = 0; h < 64; ++h) {
      float4 na0 = make_float4(0, 0, 0, 0), na1 = na0, nb0 = na0, nb1 = na0;
      if (h < 63) {
        na0 = *(const float4*)&Xp[(h + 1) * 128 + w0];
        na1 = *(const float4*)&Xp[(h + 1) * 128 + w0 + 4];
        nb0 = *(const float4*)&Xp[(h + 65) * 128 + w0];
        nb1 = *(const float4*)&Xp[(h + 65) * 128 + w0 + 4];
      }
      if (h == 32) {  // exact reset: T = e^{-2pi i kx*32/128}, quarter-turn
        __sincosf(-PI2 * (float)((kxe * 32) & 127) * (1.f / 128.f), &Tei, &Ter);
        __sincosf(-PI2 * (float)((kxo * 32) & 127) * (1.f / 128.f), &Toi, &Tor);
      }
      float xa[8] = {xa0.x, xa0.y, xa0.z, xa0.w, xa1.x, xa1.y, xa1.z, xa1.w};
      float xb[8] = {xb0.x, xb0.y, xb0.z, xb0.w, xb1.x, xb1.y, xb1.z, xb1.w};
      #pragma unroll
      for (int j = 0; j < 8; ++j) {
        float ue = xa[j] + xb[j];
        float uo = xa[j] - xb[j];
        aer[j] = fmaf(ue, Ter, aer[j]);
        aei[j] = fmaf(ue, Tei, aei[j]);
        aor[j] = fmaf(uo, Tor, aor[j]);
        aoi[j] = fmaf(uo, Toi, aoi[j]);
      }
      float ner = Ter * der - Tei * dei, nei = Ter * dei + Tei * der;
      float nor_ = Tor * dor_ - Toi * doi, noi = Tor * doi + Toi * dor_;
      Ter = ner; Tei = nei; Tor = nor_; Toi = noi;
      xa0 = na0; xa1 = na1; xb0 = nb0; xb1 = nb1;
    }
    // store A2[2kp][w0..w0+7], A2[2kp+1][w0..w0+7] as float4 pairs (r,i,r,i)
    #pragma unroll
    for (int j2 = 0; j2 < 4; ++j2) {
      int j = 2 * j2;
      *(float4*)&A2t[(kie * 130 + w0 + j) * 2] =
          make_float4(aer[j], aei[j], aer[j + 1], aei[j + 1]);
      *(float4*)&A2t[((kie + 1) * 130 + w0 + j) * 2] =
          make_float4(aor[j], aoi[j], aor[j + 1], aoi[j + 1]);
    }
  }
  __syncthreads();

  // ---- phase 2: thread = (kxi 0..31, t 0..7); ky = {t, t+8}; recurrence twiddle
  {
    const int kxi = tid >> 3;
    const int t = tid & 7;
    const float s = (t & 1) ? -1.f : 1.f;   // (-1)^ky
    float d0r, d0i, d1r, d1i;
    __sincosf(-PI2 * (float)t * (1.f / 128.f), &d0i, &d0r);
    __sincosf(-PI2 * (float)(t + 8) * (1.f / 128.f), &d1i, &d1r);
    float T0r = 1.f, T0i = 0.f, T1r = 1.f, T1i = 0.f;
    float r0 = 0.f, i0 = 0.f, r1 = 0.f, i1 = 0.f;
    #pragma unroll 4
    for (int w = 0; w < 64; ++w) {
      const float2 a = *(const float2*)&A2t[(kxi * 130 + w) * 2];
      const float2 b = *(const float2*)&A2t[(kxi * 130 + w + 64) * 2];
      float ur = fmaf(s, b.x, a.x);
      float ui = fmaf(s, b.y, a.y);
      r0 = fmaf(ur, T0r, r0); r0 = fmaf(-ui, T0i, r0);
      i0 = fmaf(ur, T0i, i0); i0 = fmaf(ui, T0r, i0);
      r1 = fmaf(ur, T1r, r1); r1 = fmaf(-ui, T1i, r1);
      i1 = fmaf(ur, T1i, i1); i1 = fmaf(ui, T1r, i1);
      float n0r = T0r * d0r - T0i * d0i, n0i = T0r * d0i + T0i * d0r;
      float n1r = T1r * d1r - T1i * d1i, n1i = T1r * d1i + T1i * d1r;
      T0r = n0r; T0i = n0i; T1r = n1r; T1i = n1i;
    }
    const float sc = 1.f / 16384.f;
    float* base = Xf + (size_t)plane * 1024 + kxi * 32;
    *(float2*)&base[t * 2]       = make_float2(r0 * sc, i0 * sc);
    *(float2*)&base[(t + 8) * 2] = make_float2(r1 * sc, i1 * sc);
  }
}

// ===========================================================================
// Kernel 2: channel mix. block = (corner 2, x 16, cg 16), c-tile of 4.
// thread = (b 16, y 16). Xf staged through LDS in 16-t chunks (coalesced).
// Y[b][c][kxi][ky][ri], same layout as Xf.
// ===========================================================================
__global__ __launch_bounds__(256) void k_mix(const float* __restrict__ Xf,
                                             const float* __restrict__ w0r,
                                             const float* __restrict__ w0i,
                                             const float* __restrict__ w1r,
                                             const float* __restrict__ w1i,
                                             float* __restrict__ Y) {
  __shared__ __attribute__((aligned(16))) float Wl[4 * 64 * 16 * 2];   // [c][t][y] f2, 32 KB
  __shared__ __attribute__((aligned(16))) float Xs[16 * 16 * 18 * 2];  // [t][b][y pad18] f2, 36 KB
  const int bid = blockIdx.x;               // 0..511
  const int c2 = bid >> 8;
  const int x  = (bid >> 4) & 15;
  const int cg = bid & 15;
  const int c0 = cg * 4;
  const int kxi = c2 * 16 + x;
  const float* Wr_g = c2 ? w1r : w0r;
  const float* Wi_g = c2 ? w1i : w0i;
  const int tid = threadIdx.x;
  const int b = tid >> 4;
  const int y = tid & 15;

  // stage weights: 4096 complex elements, coalesced (y fastest, 64B runs)
  #pragma unroll
  for (int k = 0; k < 16; ++k) {
    int idx = tid + k * 256;                // 0..4095
    int y_ = idx & 15, t_ = (idx >> 4) & 63, c_ = idx >> 10;
    size_t ga = (((size_t)(c0 + c_) * 64 + t_) * 16 + x) * 16 + y_;
    float wr = Wr_g[ga], wi = Wi_g[ga];
    Wl[idx * 2] = wr; Wl[idx * 2 + 1] = wi;
  }

  float aR[4] = {}, aI[4] = {};
  for (int tc = 0; tc < 4; ++tc) {
    __syncthreads();   // first pass: covers Wl staging; later: Xs reuse
    // stage 16-t chunk of Xf: [t][b][y], 128B-contiguous global runs
    #pragma unroll
    for (int k = 0; k < 8; ++k) {
      int idx = tid + k * 256;              // 0..2047 float4 slots
      int q = idx & 7, tb = idx >> 3;
      int t_ = tb >> 4, b_ = tb & 15;
      const float4 v = *(const float4*)&Xf[(size_t)(b_ * 64 + tc * 16 + t_) * 1024 +
                                           kxi * 32 + q * 4];
      *(float4*)&Xs[((t_ * 16 + b_) * 18 + 2 * q) * 2] = v;
    }
    __syncthreads();
    #pragma unroll
    for (int t = 0; t < 16; ++t) {
      const float2 xv = *(const float2*)&Xs[((t * 16 + b) * 18 + y) * 2];
      const int tt = tc * 16 + t;
      #pragma unroll
      for (int cj = 0; cj < 4; ++cj) {
        const float2 wv = *(const float2*)&Wl[((cj * 64 + tt) * 16 + y) * 2];
        aR[cj] = fmaf(xv.x, wv.x, aR[cj]);
        aR[cj] = fmaf(-xv.y, wv.y, aR[cj]);
        aI[cj] = fmaf(xv.x, wv.y, aI[cj]);
        aI[cj] = fmaf(xv.y, wv.x, aI[cj]);
      }
    }
  }
  #pragma unroll
  for (int cj = 0; cj < 4; ++cj) {
    size_t ya = ((size_t)(b * 64 + c0 + cj)) * 1024 + kxi * 32 + y * 2;
    *(float2*)&Y[ya] = make_float2(aR[cj], aI[cj]);
  }
}

// ===========================================================================
// Kernel 3: per (b,c) plane inverse.
// Phase A: Z[h][ky] = sum_kxi Y[kxi][ky] e^{+2pi i kx h/128}; store
//          (Mc,Ms)[h][ky] = (f*Zr, -f*Zi), f = (ky==0)?1:2.
// Phase B: out[h][w] = sum_ky Mc*cos(2pi ky w/128) + Ms*sin(...),
//          folded over w / w+64 via ky parity.
// ===========================================================================
__global__ __launch_bounds__(256) void k_inv(const float* __restrict__ Y,
                                             float* __restrict__ out) {
  __shared__ __attribute__((aligned(16))) float Yl[1024];
  __shared__ __attribute__((aligned(16))) float Ml[128 * 18 * 2];  // [h][ky(+2 pad)] f2
  const int plane = blockIdx.x;
  const int tid = threadIdx.x;
  {
    *(float4*)&Yl[tid * 4] = *(const float4*)&Y[(size_t)plane * 1024 + tid * 4];
  }
  __syncthreads();

  // ---- phase A: thread = (g 0..1 ky-half, h 0..127) ----
  {
    const int g = tid >> 7;
    const int h = tid & 127;
    float zr[8] = {}, zi[8] = {};
    float uw, uwi;   // U = e^{+2pi i h/128}
    __sincosf(PI2 * (float)h * (1.f / 128.f), &uwi, &uw);
    const float4* Yl4 = (const float4*)Yl;
    float Tr = 1.f, Ti = 0.f;
    #pragma unroll 4
    for (int kxi = 0; kxi < 16; ++kxi) {
      #pragma unroll
      for (int q = 0; q < 4; ++q) {
        float4 p = Yl4[kxi * 8 + g * 4 + q];
        int m = 2 * q;
        zr[m]   = fmaf(p.x, Tr, zr[m]);   zr[m]   = fmaf(-p.y, Ti, zr[m]);
        zi[m]   = fmaf(p.x, Ti, zi[m]);   zi[m]   = fmaf(p.y, Tr, zi[m]);
        zr[m+1] = fmaf(p.z, Tr, zr[m+1]); zr[m+1] = fmaf(-p.w, Ti, zr[m+1]);
        zi[m+1] = fmaf(p.z, Ti, zi[m+1]); zi[m+1] = fmaf(p.w, Tr, zi[m+1]);
      }
      float nr = Tr * uw - Ti * uwi, ni = Tr * uwi + Ti * uw;
      Tr = nr; Ti = ni;
    }
    __sincosf(PI2 * (float)((112 * h) & 127) * (1.f / 128.f), &Ti, &Tr);
    #pragma unroll 4
    for (int kxi = 16; kxi < 32; ++kxi) {
      #pragma unroll
      for (int q = 0; q < 4; ++q) {
        float4 p = Yl4[kxi * 8 + g * 4 + q];
        int m = 2 * q;
        zr[m]   = fmaf(p.x, Tr, zr[m]);   zr[m]   = fmaf(-p.y, Ti, zr[m]);
        zi[m]   = fmaf(p.x, Ti, zi[m]);   zi[m]   = fmaf(p.y, Tr, zi[m]);
        zr[m+1] = fmaf(p.z, Tr, zr[m+1]); zr[m+1] = fmaf(-p.w, Ti, zr[m+1]);
        zi[m+1] = fmaf(p.z, Ti, zi[m+1]); zi[m+1] = fmaf(p.w, Tr, zi[m+1]);
      }
      float nr = Tr * uw - Ti * uwi, ni = Tr * uwi + Ti * uw;
      Tr = nr; Ti = ni;
    }
    #pragma unroll
    for (int m = 0; m < 8; ++m) {
      int ky = g * 8 + m;
      float f = (ky == 0) ? 1.f : 2.f;
      int f2i = h * 18 + ky;
      Ml[f2i * 2]     =  f * zr[m];
      Ml[f2i * 2 + 1] = -f * zi[m];
    }
  }
  __syncthreads();

  // ---- phase B: thread = (hq 0..3, w 0..63); 32 h each, outputs w and w+64 ----
  {
    const int hq = tid >> 6;
    const int w = tid & 63;
    float C[16], S[16];
    {
      float cw, sw;
      __sincosf(PI2 * (float)w * (1.f / 128.f), &sw, &cw);
      C[0] = 1.f; S[0] = 0.f;
      #pragma unroll
      for (int k = 1; k < 16; ++k) {
        C[k] = C[k - 1] * cw - S[k - 1] * sw;
        S[k] = C[k - 1] * sw + S[k - 1] * cw;
      }
    }
    float* op = out + (size_t)plane * (128 * 128);
    const float4* Ml4 = (const float4*)Ml;
    #pragma unroll 2
    for (int hj = 0; hj < 32; ++hj) {
      int h = hq * 32 + hj;
      float e = 0.f, o = 0.f;
      #pragma unroll
      for (int j2 = 0; j2 < 8; ++j2) {
        float4 m01 = Ml4[h * 9 + j2];   // (Mc,Ms) for ky=2j2, 2j2+1
        int k = 2 * j2;
        float t0 = m01.x * C[k] + m01.y * S[k];
        float t1 = m01.z * C[k + 1] + m01.w * S[k + 1];
        e += t0; o += t1;
      }
      op[h * 128 + w]      = e + o;
      op[h * 128 + w + 64] = e - o;
    }
  }
}

extern "C" void kernel_launch(void* const* d_in, const int* in_sizes, int n_in,
                              void* d_out, int out_size, void* d_ws, size_t ws_size,
                              hipStream_t stream) {
  const float* X   = (const float*)d_in[0];
  const float* w0r = (const float*)d_in[1];
  const float* w0i = (const float*)d_in[2];
  const float* w1r = (const float*)d_in[3];
  const float* w1i = (const float*)d_in[4];
  float* outp = (float*)d_out;
  float* Xf = (float*)d_ws;                  // 4 MB
  float* Yw = (float*)d_ws + (1u << 20);     // 4 MB
  k_fwd<<<1024, 256, 0, stream>>>(X, Xf);
  k_mix<<<512, 256, 0, stream>>>(Xf, w0r, w0i, w1r, w1i, Yw);
  k_inv<<<1024, 256, 0, stream>>>(Yw, outp);
}